// Round 1
// baseline (695.654 us; speedup 1.0000x reference)
//
#include <hip/hip_runtime.h>
#include <hip/hip_bf16.h>

// Shapes (fixed): B=4, V=3, N=256, D=32, H=128
// Outputs (f32, concat flat):
//   node        [4,256,128]   off 0        sz 131072
//   view_lat    [4,3,256,128] off 131072   sz 393216
//   type_logits [4,256,3]     off 524288   sz 3072
//   state_pred  [4,256,4]     off 527360   sz 4096
//   e           [4,256,256]   off 531456   sz 262144
//   z(rel_mean) off 793600, z(rel_std) 1055744, z(sup_mean) 1317888,
//   z(sup_std) 1580032, z(wit_mean) 1842176, z(wit_std) 2104320
// total 2366464 floats

#define NEG_INF -1.0e9f
#define EPSC 1e-4f

__device__ __forceinline__ float logit_hint(float p) {
    p = fminf(fmaxf(p, EPSC), 1.0f - EPSC);
    return logf(p) - log1pf(-p);
}

// ---------- view encoder ----------
// h0 = relu(x @ W(32,128) + b). grid = 12*256, block = 128
__global__ void k_in_proj(const float* __restrict__ x, const float* __restrict__ W,
                          const float* __restrict__ b, float* __restrict__ h) {
    int row = blockIdx.x;           // g*256 + n
    int k = threadIdx.x;
    __shared__ float xs[32];
    if (k < 32) xs[k] = x[row * 32 + k];
    __syncthreads();
    float acc = b[k];
#pragma unroll
    for (int d = 0; d < 32; ++d) acc = fmaf(xs[d], W[d * 128 + k], acc);
    h[row * 128 + k] = fmaxf(acc, 0.f);
}

// m[g,i,k] = sum_j A[g,i,j] * h[g,j,k]. grid = 12*256, block = 128
__global__ void k_msg(const float* __restrict__ A, const float* __restrict__ h,
                      float* __restrict__ m) {
    int gi = blockIdx.x;            // g*256 + i
    int g = gi >> 8;
    int k = threadIdx.x;
    __shared__ float As[256];
    As[k] = A[gi * 256 + k];
    As[k + 128] = A[gi * 256 + k + 128];
    __syncthreads();
    const float* hg = h + g * 256 * 128;
    float acc = 0.f;
#pragma unroll 4
    for (int j = 0; j < 256; ++j) acc = fmaf(As[j], hg[j * 128 + k], acc);
    m[gi * 128 + k] = acc;
}

// h' = relu(h@W[0:128] + m@W[128:256] + b). grid = 12*256, block = 128
__global__ void k_layer(const float* __restrict__ h, const float* __restrict__ m,
                        const float* __restrict__ W, const float* __restrict__ b,
                        float* __restrict__ out) {
    int row = blockIdx.x;
    int k = threadIdx.x;
    __shared__ float hs[128], ms[128];
    hs[k] = h[row * 128 + k];
    ms[k] = m[row * 128 + k];
    __syncthreads();
    float acc = b[k];
#pragma unroll 4
    for (int d = 0; d < 128; ++d) acc = fmaf(hs[d], W[d * 128 + k], acc);
#pragma unroll 4
    for (int d = 0; d < 128; ++d) acc = fmaf(ms[d], W[(128 + d) * 128 + k], acc);
    out[row * 128 + k] = fmaxf(acc, 0.f);
}

// ---------- node fusion ----------
// grid = 4*256 (b*256+n), block = 128
__global__ void k_node(const float* __restrict__ vl, const float* __restrict__ nf0w,
                       const float* __restrict__ nf0b, const float* __restrict__ nf1w,
                       const float* __restrict__ nf1b, float* __restrict__ node_out) {
    int bn = blockIdx.x;
    int b = bn >> 8, n = bn & 255;
    int k = threadIdx.x;
    __shared__ float fused[256];
    __shared__ float g[128];
    float v0 = vl[((b * 3 + 0) * 256 + n) * 128 + k];
    float v1 = vl[((b * 3 + 1) * 256 + n) * 128 + k];
    float v2 = vl[((b * 3 + 2) * 256 + n) * 128 + k];
    float mean = (v0 + v1 + v2) * (1.f / 3.f);
    float d0 = v0 - mean, d1 = v1 - mean, d2 = v2 - mean;
    fused[k] = mean;
    fused[128 + k] = sqrtf((d0 * d0 + d1 * d1 + d2 * d2) * (1.f / 3.f));
    __syncthreads();
    float acc = nf0b[k];
#pragma unroll 4
    for (int d = 0; d < 256; ++d) acc = fmaf(fused[d], nf0w[d * 128 + k], acc);
    g[k] = fmaxf(acc, 0.f);
    __syncthreads();
    acc = nf1b[k];
#pragma unroll 4
    for (int d = 0; d < 128; ++d) acc = fmaf(g[d], nf1w[d * 128 + k], acc);
    node_out[bn * 128 + k] = acc;
}

// ---------- heads ----------
// grid = 1024, block = 128
__global__ void k_heads(const float* __restrict__ node,
                        const float* __restrict__ th0w, const float* __restrict__ th0b,
                        const float* __restrict__ th1w, const float* __restrict__ th1b,
                        const float* __restrict__ sh0w, const float* __restrict__ sh0b,
                        const float* __restrict__ sh1w, const float* __restrict__ sh1b,
                        float* __restrict__ tl, float* __restrict__ sp) {
    int bn = blockIdx.x;
    int k = threadIdx.x;
    __shared__ float ns[128], gt[128], gs[128];
    ns[k] = node[bn * 128 + k];
    __syncthreads();
    float at = th0b[k], as = sh0b[k];
#pragma unroll 4
    for (int d = 0; d < 128; ++d) {
        float nd = ns[d];
        at = fmaf(nd, th0w[d * 128 + k], at);
        as = fmaf(nd, sh0w[d * 128 + k], as);
    }
    gt[k] = fmaxf(at, 0.f);
    gs[k] = fmaxf(as, 0.f);
    __syncthreads();
    if (k < 3) {
        float a = th1b[k];
#pragma unroll 4
        for (int d = 0; d < 128; ++d) a = fmaf(gt[d], th1w[d * 3 + k], a);
        tl[bn * 3 + k] = a;
    }
    if (k >= 64 && k < 68) {
        int q = k - 64;
        float a = sh1b[q];
#pragma unroll 4
        for (int d = 0; d < 128; ++d) a = fmaf(gs[d], sh1w[d * 4 + q], a);
        sp[bn * 4 + q] = a;
    }
}

// ---------- evidence stats ----------
// one thread per (b,i,j). grid = 1024, block = 256
__global__ void k_stats(const float* __restrict__ rel, const float* __restrict__ sup,
                        const float* __restrict__ wit, const float* __restrict__ bun,
                        float* __restrict__ ev,
                        float* __restrict__ o_rm, float* __restrict__ o_rs,
                        float* __restrict__ o_sm, float* __restrict__ o_ss,
                        float* __restrict__ o_wm, float* __restrict__ o_wsd) {
    int idx = blockIdx.x * 256 + threadIdx.x;   // b*65536 + i*256 + j
    int b = idx >> 16;
    int ij = idx & 65535;
    int i = ij >> 8, j = ij & 255;
    int base = b * 3 * 65536 + ij;

    float r0 = rel[base], r1 = rel[base + 65536], r2 = rel[base + 131072];
    float s0 = sup[base], s1 = sup[base + 65536], s2 = sup[base + 131072];
    float w0 = wit[base], w1 = wit[base + 65536], w2 = wit[base + 131072];

    float rm = (r0 + r1 + r2) * (1.f / 3.f);
    float a0 = r0 - rm, a1 = r1 - rm, a2 = r2 - rm;
    float rs = sqrtf((a0 * a0 + a1 * a1 + a2 * a2) * (1.f / 3.f));
    float rmin = fminf(r0, fminf(r1, r2)), rmax = fmaxf(r0, fmaxf(r1, r2));

    float sm = (s0 + s1 + s2) * (1.f / 3.f);
    a0 = s0 - sm; a1 = s1 - sm; a2 = s2 - sm;
    float ss = sqrtf((a0 * a0 + a1 * a1 + a2 * a2) * (1.f / 3.f));
    float smin = fminf(s0, fminf(s1, s2)), smax = fmaxf(s0, fmaxf(s1, s2));

    float wm = (w0 + w1 + w2) * (1.f / 3.f);
    a0 = w0 - wm; a1 = w1 - wm; a2 = w2 - wm;
    float wsd = sqrtf((a0 * a0 + a1 * a1 + a2 * a2) * (1.f / 3.f));

    float* e = ev + idx * 18;
    e[0] = rm; e[1] = rs; e[2] = rmin; e[3] = rmax;
    e[4] = sm; e[5] = ss; e[6] = smin; e[7] = smax;
    e[8] = wm; e[9] = wsd;
    int bb = base * 4;
#pragma unroll
    for (int c = 0; c < 4; ++c) {
        float b0 = bun[bb + c], b1 = bun[bb + 262144 + c], b2 = bun[bb + 524288 + c];
        float bm = (b0 + b1 + b2) * (1.f / 3.f);
        float d0 = b0 - bm, d1 = b1 - bm, d2 = b2 - bm;
        e[10 + c] = bm;
        e[14 + c] = sqrtf((d0 * d0 + d1 * d1 + d2 * d2) * (1.f / 3.f));
    }
    bool diag = (i == j);
    o_rm[idx] = diag ? 0.f : rm;
    o_rs[idx] = diag ? 0.f : rs;
    o_sm[idx] = diag ? 0.f : sm;
    o_ss[idx] = diag ? 0.f : ss;
    o_wm[idx] = diag ? 0.f : wm;
    o_wsd[idx] = diag ? 0.f : wsd;
}

// ---------- edge head precompute: Ti = node@W_hi + eh0_b, Tj = node@W_hj ----------
// grid = 1024, block = 128
__global__ void k_titj(const float* __restrict__ node, const float* __restrict__ eh0w,
                       const float* __restrict__ eh0b, float* __restrict__ Ti,
                       float* __restrict__ Tj) {
    int bn = blockIdx.x;
    int k = threadIdx.x;
    __shared__ float ns[128];
    ns[k] = node[bn * 128 + k];
    __syncthreads();
    float ai = eh0b[k], aj = 0.f;
#pragma unroll 4
    for (int d = 0; d < 128; ++d) {
        float nd = ns[d];
        ai = fmaf(nd, eh0w[d * 128 + k], ai);
        aj = fmaf(nd, eh0w[(128 + d) * 128 + k], aj);
    }
    Ti[bn * 128 + k] = ai;
    Tj[bn * 128 + k] = aj;
}

// ---------- edge head main ----------
// block = (b, i, kq): 32 hidden units per block; 256 threads = 32 jj x 8 (4 k each)
#define S_BNN (4 * 256 * 256)
__global__ __launch_bounds__(256) void k_edge(
        const float* __restrict__ node, const float* __restrict__ Ti,
        const float* __restrict__ Tj, const float* __restrict__ ev,
        const float* __restrict__ eh0w, const float* __restrict__ eh1w,
        float* __restrict__ epart) {
    int bid = blockIdx.x;
    int kq = bid & 3;
    int bi = bid >> 2;          // b*256 + i
    int b = bi >> 8;
    int t = threadIdx.x;
    int k0 = kq * 32;

    __shared__ __attribute__((aligned(16))) float Was[128 * 32];
    __shared__ __attribute__((aligned(16))) float Wps[128 * 32];
    __shared__ __attribute__((aligned(16))) float Wevs[18 * 32];
    __shared__ __attribute__((aligned(16))) float his[128];
    __shared__ __attribute__((aligned(16))) float Tiq[32];
    __shared__ __attribute__((aligned(16))) float w1q[32];
    __shared__ __attribute__((aligned(16))) float hjs[32 * 130];
    __shared__ __attribute__((aligned(16))) float evs[32 * 18];

    for (int idx = t; idx < 128 * 32; idx += 256) {
        int d = idx >> 5, kk = idx & 31;
        Was[idx] = eh0w[(256 + d) * 128 + k0 + kk];
        Wps[idx] = eh0w[(384 + d) * 128 + k0 + kk];
    }
    for (int idx = t; idx < 18 * 32; idx += 256) {
        int c = idx >> 5, kk = idx & 31;
        Wevs[idx] = eh0w[(512 + c) * 128 + k0 + kk];
    }
    if (t < 128) his[t] = node[bi * 128 + t];
    else if (t < 160) Tiq[t - 128] = Ti[bi * 128 + k0 + (t - 128)];
    else if (t < 192) w1q[t - 160] = eh1w[k0 + (t - 160)];
    __syncthreads();

    int jj = t >> 3;
    int kk4 = (t & 7) * 4;
    int evbase = bi * 256 * 18;

    for (int j0 = 0; j0 < 256; j0 += 32) {
        for (int idx = t; idx < 32 * 128; idx += 256) {
            int r = idx >> 7, d = idx & 127;
            hjs[r * 130 + d] = node[(b * 256 + j0 + r) * 128 + d];
        }
        for (int idx = t; idx < 32 * 18; idx += 256) {
            int r = idx / 18, c = idx - r * 18;
            evs[r * 18 + c] = ev[evbase + (j0 + r) * 18 + c];
        }
        __syncthreads();

        int j = j0 + jj;
        float4 tj4 = *reinterpret_cast<const float4*>(&Tj[(b * 256 + j) * 128 + k0 + kk4]);
        float4 ti4 = *reinterpret_cast<const float4*>(&Tiq[kk4]);
        float a0 = ti4.x + tj4.x, a1 = ti4.y + tj4.y;
        float a2 = ti4.z + tj4.z, a3 = ti4.w + tj4.w;
        const float* hjrow = &hjs[jj * 130];
#pragma unroll 4
        for (int d = 0; d < 128; ++d) {
            float hid = his[d];
            float hjd = hjrow[d];
            float dif = fabsf(hid - hjd);
            float pr = hid * hjd;
            float4 wa = *reinterpret_cast<const float4*>(&Was[d * 32 + kk4]);
            float4 wp = *reinterpret_cast<const float4*>(&Wps[d * 32 + kk4]);
            a0 = fmaf(dif, wa.x, a0); a1 = fmaf(dif, wa.y, a1);
            a2 = fmaf(dif, wa.z, a2); a3 = fmaf(dif, wa.w, a3);
            a0 = fmaf(pr, wp.x, a0);  a1 = fmaf(pr, wp.y, a1);
            a2 = fmaf(pr, wp.z, a2);  a3 = fmaf(pr, wp.w, a3);
        }
        const float* evrow = &evs[jj * 18];
#pragma unroll
        for (int c = 0; c < 18; ++c) {
            float e_ = evrow[c];
            float4 we = *reinterpret_cast<const float4*>(&Wevs[c * 32 + kk4]);
            a0 = fmaf(e_, we.x, a0); a1 = fmaf(e_, we.y, a1);
            a2 = fmaf(e_, we.z, a2); a3 = fmaf(e_, we.w, a3);
        }
        float4 w1 = *reinterpret_cast<const float4*>(&w1q[kk4]);
        float sum = fmaxf(a0, 0.f) * w1.x + fmaxf(a1, 0.f) * w1.y +
                    fmaxf(a2, 0.f) * w1.z + fmaxf(a3, 0.f) * w1.w;
        sum += __shfl_down(sum, 4, 8);
        sum += __shfl_down(sum, 2, 8);
        sum += __shfl_down(sum, 1, 8);
        if ((t & 7) == 0) epart[kq * S_BNN + bi * 256 + j] = sum;
        __syncthreads();
    }
}

// ---------- final e ----------
__global__ void k_final(const float* __restrict__ ep, const float* __restrict__ rm,
                        const float* __restrict__ sm, const float* __restrict__ eh1b,
                        float* __restrict__ e_out) {
    int idx = blockIdx.x * 256 + threadIdx.x;   // b*65536 + i*256 + j
    int b = idx >> 16;
    int r = idx & 65535;
    int i = r >> 8, j = r & 255;
    int ji = (b << 16) | (j << 8) | i;
    float bias = eh1b[0];
    float s_ij = ep[idx] + ep[S_BNN + idx] + ep[2 * S_BNN + idx] + ep[3 * S_BNN + idx] +
                 bias + logit_hint(0.5f * (rm[idx] + sm[idx]));
    float s_ji = ep[ji] + ep[S_BNN + ji] + ep[2 * S_BNN + ji] + ep[3 * S_BNN + ji] +
                 bias + logit_hint(0.5f * (rm[ji] + sm[ji]));
    float val = 0.5f * (s_ij + s_ji);
    e_out[idx] = (i == j) ? NEG_INF : val;
}

extern "C" void kernel_launch(void* const* d_in, const int* in_sizes, int n_in,
                              void* d_out, int out_size, void* d_ws, size_t ws_size,
                              hipStream_t stream) {
    const float* slots = (const float*)d_in[0];
    const float* rel   = (const float*)d_in[1];
    const float* sup   = (const float*)d_in[2];
    const float* wit   = (const float*)d_in[3];
    const float* bun   = (const float*)d_in[4];
    const float* ve_in_w = (const float*)d_in[5];
    const float* ve_in_b = (const float*)d_in[6];
    const float* ve_w[3] = {(const float*)d_in[7], (const float*)d_in[9], (const float*)d_in[11]};
    const float* ve_b[3] = {(const float*)d_in[8], (const float*)d_in[10], (const float*)d_in[12]};
    const float* nf0w = (const float*)d_in[13];
    const float* nf0b = (const float*)d_in[14];
    const float* nf1w = (const float*)d_in[15];
    const float* nf1b = (const float*)d_in[16];
    const float* th0w = (const float*)d_in[17];
    const float* th0b = (const float*)d_in[18];
    const float* th1w = (const float*)d_in[19];
    const float* th1b = (const float*)d_in[20];
    const float* sh0w = (const float*)d_in[21];
    const float* sh0b = (const float*)d_in[22];
    const float* sh1w = (const float*)d_in[23];
    const float* sh1b = (const float*)d_in[24];
    const float* eh0w = (const float*)d_in[25];
    const float* eh0b = (const float*)d_in[26];
    const float* eh1w = (const float*)d_in[27];
    const float* eh1b = (const float*)d_in[28];

    float* out = (float*)d_out;
    float* o_node = out;
    float* o_vl   = out + 131072;
    float* o_tl   = out + 524288;
    float* o_sp   = out + 527360;
    float* o_e    = out + 531456;
    float* o_rm   = out + 793600;
    float* o_rs   = out + 1055744;
    float* o_sm   = out + 1317888;
    float* o_ss   = out + 1580032;
    float* o_wm   = out + 1842176;
    float* o_wsd  = out + 2104320;

    float* ws  = (float*)d_ws;
    float* h_a = ws;                  // 393216
    float* h_b = ws + 393216;         // 393216
    float* m   = ws + 786432;         // 393216
    float* Ti  = ws + 1179648;        // 131072
    float* Tj  = ws + 1310720;        // 131072
    float* ev  = ws + 1441792;        // 4718592
    float* ep  = ws + 6160384;        // 1048576  (total 7208960 floats = 28.8 MB)

    k_in_proj<<<3072, 128, 0, stream>>>(slots, ve_in_w, ve_in_b, h_a);

    k_msg<<<3072, 128, 0, stream>>>(rel, h_a, m);
    k_layer<<<3072, 128, 0, stream>>>(h_a, m, ve_w[0], ve_b[0], h_b);
    k_msg<<<3072, 128, 0, stream>>>(rel, h_b, m);
    k_layer<<<3072, 128, 0, stream>>>(h_b, m, ve_w[1], ve_b[1], h_a);
    k_msg<<<3072, 128, 0, stream>>>(rel, h_a, m);
    k_layer<<<3072, 128, 0, stream>>>(h_a, m, ve_w[2], ve_b[2], o_vl);

    k_node<<<1024, 128, 0, stream>>>(o_vl, nf0w, nf0b, nf1w, nf1b, o_node);
    k_heads<<<1024, 128, 0, stream>>>(o_node, th0w, th0b, th1w, th1b,
                                      sh0w, sh0b, sh1w, sh1b, o_tl, o_sp);
    k_stats<<<1024, 256, 0, stream>>>(rel, sup, wit, bun, ev,
                                      o_rm, o_rs, o_sm, o_ss, o_wm, o_wsd);
    k_titj<<<1024, 128, 0, stream>>>(o_node, eh0w, eh0b, Ti, Tj);
    k_edge<<<4096, 256, 0, stream>>>(o_node, Ti, Tj, ev, eh0w, eh1w, ep);
    k_final<<<1024, 256, 0, stream>>>(ep, o_rm, o_sm, eh1b, o_e);
}

// Round 2
// 246.262 us; speedup vs baseline: 2.8249x; 2.8249x over previous
//
#include <hip/hip_runtime.h>
#include <hip/hip_bf16.h>

// Shapes (fixed): B=4, V=3, N=256, D=32, H=128
// Outputs (f32, concat flat): node[131072] vl[393216] tl[3072] sp[4096]
//   e[262144] z_rm z_rs z_sm z_ss z_wm z_wsd (262144 each)

#define NEG_INF -1.0e9f
#define EPSC 1e-4f

typedef __attribute__((ext_vector_type(8))) short short8;
typedef __attribute__((ext_vector_type(4))) float f32x4;

__device__ __forceinline__ float logit_hint(float p) {
    p = fminf(fmaxf(p, EPSC), 1.0f - EPSC);
    return logf(p) - log1pf(-p);
}
__device__ __forceinline__ unsigned short f2bf(float v) {
    unsigned int u = __builtin_bit_cast(unsigned int, v);
    u += 0x7fffu + ((u >> 16) & 1u);
    return (unsigned short)(u >> 16);
}
__device__ __forceinline__ float bf2f(unsigned short h) {
    return __builtin_bit_cast(float, (unsigned int)h << 16);
}

// ---------- view encoder ----------
__global__ void k_in_proj(const float* __restrict__ x, const float* __restrict__ W,
                          const float* __restrict__ b, float* __restrict__ h) {
    int row = blockIdx.x;           // g*256 + n
    int k = threadIdx.x;
    __shared__ float xs[32];
    if (k < 32) xs[k] = x[row * 32 + k];
    __syncthreads();
    float acc = b[k];
#pragma unroll
    for (int d = 0; d < 32; ++d) acc = fmaf(xs[d], W[d * 128 + k], acc);
    h[row * 128 + k] = fmaxf(acc, 0.f);
}

__global__ void k_msg(const float* __restrict__ A, const float* __restrict__ h,
                      float* __restrict__ m) {
    int gi = blockIdx.x;            // g*256 + i
    int g = gi >> 8;
    int k = threadIdx.x;
    __shared__ float As[256];
    As[k] = A[gi * 256 + k];
    As[k + 128] = A[gi * 256 + k + 128];
    __syncthreads();
    const float* hg = h + g * 256 * 128;
    float acc = 0.f;
#pragma unroll 4
    for (int j = 0; j < 256; ++j) acc = fmaf(As[j], hg[j * 128 + k], acc);
    m[gi * 128 + k] = acc;
}

__global__ void k_layer(const float* __restrict__ h, const float* __restrict__ m,
                        const float* __restrict__ W, const float* __restrict__ b,
                        float* __restrict__ out) {
    int row = blockIdx.x;
    int k = threadIdx.x;
    __shared__ float hs[128], ms[128];
    hs[k] = h[row * 128 + k];
    ms[k] = m[row * 128 + k];
    __syncthreads();
    float acc = b[k];
#pragma unroll 4
    for (int d = 0; d < 128; ++d) acc = fmaf(hs[d], W[d * 128 + k], acc);
#pragma unroll 4
    for (int d = 0; d < 128; ++d) acc = fmaf(ms[d], W[(128 + d) * 128 + k], acc);
    out[row * 128 + k] = fmaxf(acc, 0.f);
}

// ---------- node fusion (also emits bf16 node panel in frag-linear layout) ----------
__global__ void k_node(const float* __restrict__ vl, const float* __restrict__ nf0w,
                       const float* __restrict__ nf0b, const float* __restrict__ nf1w,
                       const float* __restrict__ nf1b, float* __restrict__ node_out,
                       unsigned short* __restrict__ nodeS_g) {
    int bn = blockIdx.x;
    int b = bn >> 8, n = bn & 255;
    int k = threadIdx.x;
    __shared__ float fused[256];
    __shared__ float g[128];
    float v0 = vl[((b * 3 + 0) * 256 + n) * 128 + k];
    float v1 = vl[((b * 3 + 1) * 256 + n) * 128 + k];
    float v2 = vl[((b * 3 + 2) * 256 + n) * 128 + k];
    float mean = (v0 + v1 + v2) * (1.f / 3.f);
    float d0 = v0 - mean, d1 = v1 - mean, d2 = v2 - mean;
    fused[k] = mean;
    fused[128 + k] = sqrtf((d0 * d0 + d1 * d1 + d2 * d2) * (1.f / 3.f));
    __syncthreads();
    float acc = nf0b[k];
#pragma unroll 4
    for (int d = 0; d < 256; ++d) acc = fmaf(fused[d], nf0w[d * 128 + k], acc);
    g[k] = fmaxf(acc, 0.f);
    __syncthreads();
    acc = nf1b[k];
#pragma unroll 4
    for (int d = 0; d < 128; ++d) acc = fmaf(g[d], nf1w[d * 128 + k], acc);
    node_out[bn * 128 + k] = acc;
    // nodeS[b][jt=n>>4][gp=k>>3][l15=n&15][e=k&7] = bf16(node[b][n][k])
    nodeS_g[b * 32768 + (n >> 4) * 2048 + (k >> 3) * 128 + (n & 15) * 8 + (k & 7)] =
        f2bf(acc);
}

// ---------- heads ----------
__global__ void k_heads(const float* __restrict__ node,
                        const float* __restrict__ th0w, const float* __restrict__ th0b,
                        const float* __restrict__ th1w, const float* __restrict__ th1b,
                        const float* __restrict__ sh0w, const float* __restrict__ sh0b,
                        const float* __restrict__ sh1w, const float* __restrict__ sh1b,
                        float* __restrict__ tl, float* __restrict__ sp) {
    int bn = blockIdx.x;
    int k = threadIdx.x;
    __shared__ float ns[128], gt[128], gs[128];
    ns[k] = node[bn * 128 + k];
    __syncthreads();
    float at = th0b[k], as = sh0b[k];
#pragma unroll 4
    for (int d = 0; d < 128; ++d) {
        float nd = ns[d];
        at = fmaf(nd, th0w[d * 128 + k], at);
        as = fmaf(nd, sh0w[d * 128 + k], as);
    }
    gt[k] = fmaxf(at, 0.f);
    gs[k] = fmaxf(as, 0.f);
    __syncthreads();
    if (k < 3) {
        float a = th1b[k];
#pragma unroll 4
        for (int d = 0; d < 128; ++d) a = fmaf(gt[d], th1w[d * 3 + k], a);
        tl[bn * 3 + k] = a;
    }
    if (k >= 64 && k < 68) {
        int q = k - 64;
        float a = sh1b[q];
#pragma unroll 4
        for (int d = 0; d < 128; ++d) a = fmaf(gs[d], sh1w[d * 4 + q], a);
        sp[bn * 4 + q] = a;
    }
}

// ---------- evidence stats (writes bf16 ev rows padded to 32) ----------
__global__ void k_stats(const float* __restrict__ rel, const float* __restrict__ sup,
                        const float* __restrict__ wit, const float* __restrict__ bun,
                        unsigned short* __restrict__ ev_bf,
                        float* __restrict__ o_rm, float* __restrict__ o_rs,
                        float* __restrict__ o_sm, float* __restrict__ o_ss,
                        float* __restrict__ o_wm, float* __restrict__ o_wsd) {
    int idx = blockIdx.x * 256 + threadIdx.x;   // b*65536 + i*256 + j
    int b = idx >> 16;
    int ij = idx & 65535;
    int i = ij >> 8, j = ij & 255;
    int base = b * 3 * 65536 + ij;

    float r0 = rel[base], r1 = rel[base + 65536], r2 = rel[base + 131072];
    float s0 = sup[base], s1 = sup[base + 65536], s2 = sup[base + 131072];
    float w0 = wit[base], w1 = wit[base + 65536], w2 = wit[base + 131072];

    float rm = (r0 + r1 + r2) * (1.f / 3.f);
    float a0 = r0 - rm, a1 = r1 - rm, a2 = r2 - rm;
    float rs = sqrtf((a0 * a0 + a1 * a1 + a2 * a2) * (1.f / 3.f));
    float rmin = fminf(r0, fminf(r1, r2)), rmax = fmaxf(r0, fmaxf(r1, r2));

    float sm = (s0 + s1 + s2) * (1.f / 3.f);
    a0 = s0 - sm; a1 = s1 - sm; a2 = s2 - sm;
    float ss = sqrtf((a0 * a0 + a1 * a1 + a2 * a2) * (1.f / 3.f));
    float smin = fminf(s0, fminf(s1, s2)), smax = fmaxf(s0, fmaxf(s1, s2));

    float wm = (w0 + w1 + w2) * (1.f / 3.f);
    a0 = w0 - wm; a1 = w1 - wm; a2 = w2 - wm;
    float wsd = sqrtf((a0 * a0 + a1 * a1 + a2 * a2) * (1.f / 3.f));

    union { unsigned short us[32]; uint4 q[4]; } pk;
    pk.us[0] = f2bf(rm);  pk.us[1] = f2bf(rs);
    pk.us[2] = f2bf(rmin); pk.us[3] = f2bf(rmax);
    pk.us[4] = f2bf(sm);  pk.us[5] = f2bf(ss);
    pk.us[6] = f2bf(smin); pk.us[7] = f2bf(smax);
    pk.us[8] = f2bf(wm);  pk.us[9] = f2bf(wsd);
    int bb = base * 4;
#pragma unroll
    for (int c = 0; c < 4; ++c) {
        float b0 = bun[bb + c], b1 = bun[bb + 262144 + c], b2 = bun[bb + 524288 + c];
        float bm = (b0 + b1 + b2) * (1.f / 3.f);
        float d0 = b0 - bm, d1 = b1 - bm, d2 = b2 - bm;
        pk.us[10 + c] = f2bf(bm);
        pk.us[14 + c] = f2bf(sqrtf((d0 * d0 + d1 * d1 + d2 * d2) * (1.f / 3.f)));
    }
#pragma unroll
    for (int c = 18; c < 32; ++c) pk.us[c] = 0;
    uint4* dst = (uint4*)&ev_bf[(size_t)idx * 32];
    dst[0] = pk.q[0]; dst[1] = pk.q[1]; dst[2] = pk.q[2]; dst[3] = pk.q[3];

    bool diag = (i == j);
    o_rm[idx] = diag ? 0.f : rm;
    o_rs[idx] = diag ? 0.f : rs;
    o_sm[idx] = diag ? 0.f : sm;
    o_ss[idx] = diag ? 0.f : ss;
    o_wm[idx] = diag ? 0.f : wm;
    o_wsd[idx] = diag ? 0.f : wsd;
}

// ---------- Ti = node@W_hi + eh0_b (f32), Tjt[b][k][j] = bf16(node_j@W_hj) ----------
__global__ void k_titj(const float* __restrict__ node, const float* __restrict__ eh0w,
                       const float* __restrict__ eh0b, float* __restrict__ Ti,
                       unsigned short* __restrict__ Tjt) {
    int bn = blockIdx.x;
    int b = bn >> 8, n = bn & 255;
    int k = threadIdx.x;
    __shared__ float ns[128];
    ns[k] = node[bn * 128 + k];
    __syncthreads();
    float ai = eh0b[k], aj = 0.f;
#pragma unroll 4
    for (int d = 0; d < 128; ++d) {
        float nd = ns[d];
        ai = fmaf(nd, eh0w[d * 128 + k], ai);
        aj = fmaf(nd, eh0w[(128 + d) * 128 + k], aj);
    }
    Ti[bn * 128 + k] = ai;
    Tjt[((size_t)(b * 128 + k)) * 256 + n] = f2bf(aj);
}

// ---------- stage edge-head weights (rows 256..529 of eh0w) in frag-ready order ----------
// Bs[kk][n][lane][e] = bf16(eh0w[(256 + 32kk + 8(lane>>4) + e)][16n + (lane&15)]), 0 if kf>=274
__global__ void k_prep_bs(const float* __restrict__ eh0w, unsigned short* __restrict__ Bs_g) {
    int idx = blockIdx.x * 256 + threadIdx.x;  // 36864
    int kk = idx >> 12;
    int rem = idx & 4095;
    int n = rem >> 9;
    int l = (rem >> 3) & 63;
    int e = idx & 7;
    int kf = 32 * kk + 8 * (l >> 4) + e;
    int col = 16 * n + (l & 15);
    float v = (kf < 274) ? eh0w[(256 + kf) * 128 + col] : 0.f;
    Bs_g[idx] = f2bf(v);
}

// ---------- edge head: MFMA ----------
// block = (b, i-pair): 8 waves, wave w -> i = i0+(w>>2), j-chunk = (w&3)*64
// A[j][K=288]: [ |hi-hj| 128 | hi*hj 128 | ev 18 | pad 14 ], B = staged weights
__global__ __launch_bounds__(512, 2) void k_edge(
        const unsigned short* __restrict__ nodeS_g,
        const unsigned short* __restrict__ Bs_g,
        const unsigned short* __restrict__ ev_bf,
        const unsigned short* __restrict__ Tjt,
        const float* __restrict__ Ti_g, const float* __restrict__ eh1w,
        float* __restrict__ ep) {
    __shared__ short lds[69632];   // node panel 32768 hw + Bs 36864 hw = 139264 B
    int tid = threadIdx.x;
    int blk = blockIdx.x;
    int b = blk >> 7;
    int i0 = (blk & 127) << 1;

    {   // stage: both source layouts are identical to LDS layouts (linear copy)
        const short8* srcN = (const short8*)(nodeS_g + (size_t)b * 32768);
        short8* dstN = (short8*)lds;
        for (int t = tid; t < 4096; t += 512) dstN[t] = srcN[t];
        const short8* srcB = (const short8*)Bs_g;
        short8* dstB = (short8*)(lds + 32768);
        for (int t = tid; t < 4608; t += 512) dstB[t] = srcB[t];
    }
    __syncthreads();

    int w = tid >> 6, lane = tid & 63;
    int i = i0 + (w >> 2);
    int j0 = (w & 3) << 6;
    int g = lane >> 4, l15 = lane & 15;
    int bi = b * 256 + i;

    float ti[8], w1r[8];
#pragma unroll
    for (int n = 0; n < 8; ++n) {
        ti[n] = Ti_g[bi * 128 + 16 * n + l15];
        w1r[n] = eh1w[16 * n + l15];
    }

    f32x4 acc[4][8];
#pragma unroll
    for (int m = 0; m < 4; ++m)
#pragma unroll
        for (int n = 0; n < 8; ++n) acc[m][n] = (f32x4){0.f, 0.f, 0.f, 0.f};

    int jt0 = j0 >> 4;
    int jti = i >> 4;

    for (int kk = 0; kk < 8; ++kk) {
        int kkm = kk & 3;
        bool isPr = kk >= 4;
        short8 bfr[8];
#pragma unroll
        for (int n = 0; n < 8; ++n)
            bfr[n] = *(const short8*)&lds[32768 + ((kk * 8 + n) * 64 + lane) * 8];
        short8 hi8 = *(const short8*)&lds[jti * 2048 + kkm * 512 + g * 128 + (i & 15) * 8];
        float hif[8];
#pragma unroll
        for (int e = 0; e < 8; ++e) hif[e] = bf2f((unsigned short)hi8[e]);
#pragma unroll
        for (int m = 0; m < 4; ++m) {
            short8 hj8 = *(const short8*)&lds[(jt0 + m) * 2048 + kkm * 512 + lane * 8];
            short8 a;
#pragma unroll
            for (int e = 0; e < 8; ++e) {
                float hj = bf2f((unsigned short)hj8[e]);
                float v = isPr ? hif[e] * hj : fabsf(hif[e] - hj);
                a[e] = (short)f2bf(v);
            }
#pragma unroll
            for (int n = 0; n < 8; ++n)
                acc[m][n] = __builtin_amdgcn_mfma_f32_16x16x32_bf16(a, bfr[n], acc[m][n], 0, 0, 0);
        }
    }
    {   // kk = 8: ev features straight from ev_bf (already bf16, padded to 32)
        short8 bfr[8];
#pragma unroll
        for (int n = 0; n < 8; ++n)
            bfr[n] = *(const short8*)&lds[32768 + ((64 + n) * 64 + lane) * 8];
#pragma unroll
        for (int m = 0; m < 4; ++m) {
            int j = j0 + 16 * m + l15;
            short8 a = *(const short8*)&ev_bf[((size_t)(bi * 256 + j)) * 32 + 8 * g];
#pragma unroll
            for (int n = 0; n < 8; ++n)
                acc[m][n] = __builtin_amdgcn_mfma_f32_16x16x32_bf16(a, bfr[n], acc[m][n], 0, 0, 0);
        }
    }
    // epilogue: + Ti[k] + Tj[j][k], relu, * w1[k], reduce over k, write e_pre
#pragma unroll
    for (int m = 0; m < 4; ++m) {
        int jb = j0 + 16 * m + 4 * g;
        float s0 = 0.f, s1 = 0.f, s2 = 0.f, s3 = 0.f;
#pragma unroll
        for (int n = 0; n < 8; ++n) {
            int k = 16 * n + l15;
            uint2 tj = *(const uint2*)&Tjt[((size_t)(b * 128 + k)) * 256 + jb];
            float tb = ti[n];
            float h0 = acc[m][n][0] + tb + bf2f((unsigned short)(tj.x & 0xffff));
            float h1 = acc[m][n][1] + tb + bf2f((unsigned short)(tj.x >> 16));
            float h2 = acc[m][n][2] + tb + bf2f((unsigned short)(tj.y & 0xffff));
            float h3 = acc[m][n][3] + tb + bf2f((unsigned short)(tj.y >> 16));
            float wk = w1r[n];
            s0 += fmaxf(h0, 0.f) * wk;
            s1 += fmaxf(h1, 0.f) * wk;
            s2 += fmaxf(h2, 0.f) * wk;
            s3 += fmaxf(h3, 0.f) * wk;
        }
#pragma unroll
        for (int mk = 1; mk < 16; mk <<= 1) {
            s0 += __shfl_xor(s0, mk);
            s1 += __shfl_xor(s1, mk);
            s2 += __shfl_xor(s2, mk);
            s3 += __shfl_xor(s3, mk);
        }
        if (l15 == 0)
            *(float4*)&ep[(size_t)bi * 256 + jb] = make_float4(s0, s1, s2, s3);
    }
}

// ---------- final e ----------
__global__ void k_final(const float* __restrict__ ep, const float* __restrict__ rm,
                        const float* __restrict__ sm, const float* __restrict__ eh1b,
                        float* __restrict__ e_out) {
    int idx = blockIdx.x * 256 + threadIdx.x;   // b*65536 + i*256 + j
    int b = idx >> 16;
    int r = idx & 65535;
    int i = r >> 8, j = r & 255;
    int ji = (b << 16) | (j << 8) | i;
    float bias = eh1b[0];
    float s_ij = ep[idx] + bias + logit_hint(0.5f * (rm[idx] + sm[idx]));
    float s_ji = ep[ji] + bias + logit_hint(0.5f * (rm[ji] + sm[ji]));
    float val = 0.5f * (s_ij + s_ji);
    e_out[idx] = (i == j) ? NEG_INF : val;
}

extern "C" void kernel_launch(void* const* d_in, const int* in_sizes, int n_in,
                              void* d_out, int out_size, void* d_ws, size_t ws_size,
                              hipStream_t stream) {
    const float* slots = (const float*)d_in[0];
    const float* rel   = (const float*)d_in[1];
    const float* sup   = (const float*)d_in[2];
    const float* wit   = (const float*)d_in[3];
    const float* bun   = (const float*)d_in[4];
    const float* ve_in_w = (const float*)d_in[5];
    const float* ve_in_b = (const float*)d_in[6];
    const float* ve_w[3] = {(const float*)d_in[7], (const float*)d_in[9], (const float*)d_in[11]};
    const float* ve_b[3] = {(const float*)d_in[8], (const float*)d_in[10], (const float*)d_in[12]};
    const float* nf0w = (const float*)d_in[13];
    const float* nf0b = (const float*)d_in[14];
    const float* nf1w = (const float*)d_in[15];
    const float* nf1b = (const float*)d_in[16];
    const float* th0w = (const float*)d_in[17];
    const float* th0b = (const float*)d_in[18];
    const float* th1w = (const float*)d_in[19];
    const float* th1b = (const float*)d_in[20];
    const float* sh0w = (const float*)d_in[21];
    const float* sh0b = (const float*)d_in[22];
    const float* sh1w = (const float*)d_in[23];
    const float* sh1b = (const float*)d_in[24];
    const float* eh0w = (const float*)d_in[25];
    const float* eh0b = (const float*)d_in[26];
    const float* eh1w = (const float*)d_in[27];
    const float* eh1b = (const float*)d_in[28];

    float* out = (float*)d_out;
    float* o_node = out;
    float* o_vl   = out + 131072;
    float* o_tl   = out + 524288;
    float* o_sp   = out + 527360;
    float* o_e    = out + 531456;
    float* o_rm   = out + 793600;
    float* o_rs   = out + 1055744;
    float* o_sm   = out + 1317888;
    float* o_ss   = out + 1580032;
    float* o_wm   = out + 1842176;
    float* o_wsd  = out + 2104320;

    float* ws  = (float*)d_ws;
    float* h_a = ws;                                  // 393216
    float* h_b = ws + 393216;                         // 393216
    float* m   = ws + 786432;                         // 393216
    float* Ti  = ws + 1179648;                        // 131072
    float* ep  = ws + 1310720;                        // 262144
    unsigned short* ev_bf  = (unsigned short*)(ws + 1572864);  // 8388608 hw
    unsigned short* Tjt    = (unsigned short*)(ws + 5767168);  // 131072 hw
    unsigned short* nodeSg = (unsigned short*)(ws + 5832704);  // 131072 hw
    unsigned short* Bs_g   = (unsigned short*)(ws + 5898240);  // 36864 hw
    // end: 5916672 floats = 23.7 MB

    k_in_proj<<<3072, 128, 0, stream>>>(slots, ve_in_w, ve_in_b, h_a);
    k_msg<<<3072, 128, 0, stream>>>(rel, h_a, m);
    k_layer<<<3072, 128, 0, stream>>>(h_a, m, ve_w[0], ve_b[0], h_b);
    k_msg<<<3072, 128, 0, stream>>>(rel, h_b, m);
    k_layer<<<3072, 128, 0, stream>>>(h_b, m, ve_w[1], ve_b[1], h_a);
    k_msg<<<3072, 128, 0, stream>>>(rel, h_a, m);
    k_layer<<<3072, 128, 0, stream>>>(h_a, m, ve_w[2], ve_b[2], o_vl);

    k_node<<<1024, 128, 0, stream>>>(o_vl, nf0w, nf0b, nf1w, nf1b, o_node, nodeSg);
    k_heads<<<1024, 128, 0, stream>>>(o_node, th0w, th0b, th1w, th1b,
                                      sh0w, sh0b, sh1w, sh1b, o_tl, o_sp);
    k_stats<<<1024, 256, 0, stream>>>(rel, sup, wit, bun, ev_bf,
                                      o_rm, o_rs, o_sm, o_ss, o_wm, o_wsd);
    k_titj<<<1024, 128, 0, stream>>>(o_node, eh0w, eh0b, Ti, Tjt);
    k_prep_bs<<<144, 256, 0, stream>>>(eh0w, Bs_g);
    k_edge<<<512, 512, 0, stream>>>(nodeSg, Bs_g, ev_bf, Tjt, Ti, eh1w, ep);
    k_final<<<1024, 256, 0, stream>>>(ep, o_rm, o_sm, eh1b, o_e);
}